// Round 11
// baseline (52.836 us; speedup 1.0000x reference)
//
#include <hip/hip_runtime.h>

// Bilinear flow warp, LDS row-tile v7: clean TH=16 retest (R8 redo).
// images [32,3,512,512] f32, flows [32,2,512,512] f32 (ch0=dy, ch1=dx).
//
// R10 post-mortem: counted-vmcnt pipeline neutral (45.8 vs 44.4) -> barrier
// drain exonerated; plateau = sum of pipe work (LDS gather 26K + conflicts
// 18K + VMEM 28K + VALU 17K ~= 89K of 106K cy/CU). Largest reducible term:
// staging redundancy (2.0x). R8's TH=16 test was invalid: launch_bounds
// (1024,8) pinned VGPR=32 -> spills (WRITE_SIZE 196MB). But R8 showed 73-75%
// occupancy vs 40% for all 512-thread variants -> structure is good, spills
// killed it. This: TH=16, 1024 thr, launch_bounds(1024,2) (VGPR cap 128,
// natural ~60, no spill), HALO=4 (24 rows = 1.5x redundancy, reads -19%,
// stage instrs 12->9/wave), single buffer + __syncthreads (R6 structure).

constexpr int C = 3, H = 512, W = 512, HW = H * W;
constexpr int TH = 16, HALO = 4;
constexpr int LROWS = TH + 2 * HALO;      // 24 staged rows
constexpr int LWP   = W;                  // 512: stride == 0 mod 32 banks
constexpr int TILES = 32 * (H / TH);      // 1024 blocks, %8 == 0

__global__ __launch_bounds__(1024, 2) void warp_bilinear_rows(
    const float* __restrict__ images,
    const float* __restrict__ flows,
    float* __restrict__ out)
{
    __shared__ float tile[LROWS * LWP];   // 49,152 B -> 2 blocks/CU

    // XCD-contiguous: XCD r owns tiles [r*128,(r+1)*128) = 4 whole batches.
    int bid = blockIdx.x;
    int tile_id = (bid & 7) * (TILES / 8) + (bid >> 3);
    int b   = tile_id >> 5;               // 32 strips per batch
    int ty0 = (tile_id & 31) * TH;

    int tid  = threadIdx.x;               // 0..1023
    int xg   = tid & 511;                 // my column
    int half = tid >> 9;                  // 0/1: which 8-row half I own
    int yb   = ty0 + half * 8;            // my first output row

    // ---- flow load + channel-independent gather state (8 px/thread) ----
    const float* flow_y = flows + (size_t)b * 2 * HW + yb * W + xg;
    const float* flow_x = flow_y + HW;

    float dxv[8], dyv[8];
    int   li[8];
    unsigned okm = 0;
#pragma unroll
    for (int k = 0; k < 8; ++k) {
        float fy = flow_y[k * W];
        float fx = flow_x[k * W];
        float sx = fminf(fmaxf((float)xg + fx, 0.0f), (float)(W - 1));
        float sy = fminf(fmaxf((float)(yb + k) + fy, 0.0f), (float)(H - 1));
        int x0 = min((int)sx, W - 2);     // sx >= 0 so (int) == floor
        int y0 = min((int)sy, H - 2);
        dxv[k] = sx - (float)x0;
        dyv[k] = sy - (float)y0;
        int ly0 = y0 - (ty0 - HALO);
        bool ok = (ly0 >= 0) & (ly0 <= LROWS - 2);
        okm |= (unsigned)ok << k;
        li[k] = ok ? (ly0 * LWP + x0)     // LDS offset (x needs no halo)
                   : (y0 * W + x0);       // global fallback offset
    }
    bool fast = __all(okm == 0xFFu);

    // staging addresses (channel-invariant): wave-uniform row + lane*16B
    //   iter it covers rows it*8 + (tid>>7); cols (tid&127)*4 .. +3
    int srow[LROWS / 8];
    int scol = (tid & 127) * 4;
#pragma unroll
    for (int it = 0; it < LROWS / 8; ++it) {      // 3 iters, 8 rows each
        int r = it * 8 + (tid >> 7);
        srow[it] = min(max(ty0 - HALO + r, 0), H - 1);
    }

    for (int c = 0; c < C; ++c) {
        const float* gimg = images + ((size_t)b * C + c) * HW;
        __syncthreads();                  // previous channel's reads done
#pragma unroll
        for (int it = 0; it < LROWS / 8; ++it) {
            int r = it * 8 + (tid >> 7);
            __builtin_amdgcn_global_load_lds(
                (const __attribute__((address_space(1))) void*)(gimg + srow[it] * W + scol),
                (__attribute__((address_space(3))) void*)(&tile[r * LWP + scol]),
                16, 0, 0);
        }
        __syncthreads();                  // drains vmcnt -> tile ready

        float* outc = out + ((size_t)b * C + c) * HW + yb * W + xg;
        if (fast) {
#pragma unroll
            for (int k = 0; k < 8; ++k) {
                float dx = dxv[k], dy = dyv[k];
                float wa = (1.0f - dx) * (1.0f - dy);
                float wb = (1.0f - dx) * dy;
                float wc = dx * (1.0f - dy);
                float wd = dx * dy;
                int t = li[k];
                float Ia = tile[t];        float Ic = tile[t + 1];
                float Ib = tile[t + LWP];  float Id = tile[t + LWP + 1];
                __builtin_nontemporal_store(
                    wa * Ia + wb * Ib + wc * Ic + wd * Id, outc + k * W);
            }
        } else {                           // rare: |dy| > ~4 near strip edge
#pragma unroll
            for (int k = 0; k < 8; ++k) {
                float dx = dxv[k], dy = dyv[k];
                float wa = (1.0f - dx) * (1.0f - dy);
                float wb = (1.0f - dx) * dy;
                float wc = dx * (1.0f - dy);
                float wd = dx * dy;
                float Ia, Ib, Ic, Id;
                if ((okm >> k) & 1) {
                    int t = li[k];
                    Ia = tile[t];        Ic = tile[t + 1];
                    Ib = tile[t + LWP];  Id = tile[t + LWP + 1];
                } else {
                    int g = li[k];
                    Ia = gimg[g];        Ic = gimg[g + 1];
                    Ib = gimg[g + W];    Id = gimg[g + W + 1];
                }
                __builtin_nontemporal_store(
                    wa * Ia + wb * Ib + wc * Ic + wd * Id, outc + k * W);
            }
        }
    }
}

extern "C" void kernel_launch(void* const* d_in, const int* in_sizes, int n_in,
                              void* d_out, int out_size, void* d_ws, size_t ws_size,
                              hipStream_t stream) {
    const float* images = (const float*)d_in[0];
    const float* flows  = (const float*)d_in[1];
    float* out = (float*)d_out;

    dim3 block(1024);
    dim3 grid(TILES);                     // 1024 blocks
    hipLaunchKernelGGL(warp_bilinear_rows, grid, block, 0, stream,
                       images, flows, out);
}

// Round 13
// 46.904 us; speedup vs baseline: 1.1265x; 1.1265x over previous
//
#include <hip/hip_runtime.h>

// Bilinear flow warp, LDS row-tile v8b: 2-col x 8-row patches, float2 I/O.
// images [32,3,512,512] f32, flows [32,2,512,512] f32 (ch0=dy, ch1=dx).
//
// R12 post-mortem: compile error only -- __builtin_nontemporal_store rejects
// HIP's float2 (struct, not clang vector). Fixed with a native
// ext_vector_type(2) float. Theory unchanged from R11: cut VMEM instruction
// count (3328 -> ~2048/CU) by making flow loads and output stores 8B/lane.
// LDS gather count/banking unchanged. If neutral, structure is at plateau.

typedef float f32x2 __attribute__((ext_vector_type(2)));

constexpr int C = 3, H = 512, W = 512, HW = H * W;
constexpr int TH = 8, HALO = 4;
constexpr int LROWS = TH + 2 * HALO;      // 16 staged rows
constexpr int LWP   = W;                  // 512: stride == 0 mod 32 banks
constexpr int TILES = 32 * (H / TH);      // 2048 blocks, %8 == 0

__global__ __launch_bounds__(256) void warp_bilinear_rows(
    const float* __restrict__ images,
    const float* __restrict__ flows,
    float* __restrict__ out)
{
    __shared__ float tile[LROWS * LWP];   // 32,768 B

    // XCD-contiguous: XCD r owns tiles [r*256,(r+1)*256) = 4 whole batches.
    int bid = blockIdx.x;
    int tile_id = (bid & 7) * (TILES / 8) + (bid >> 3);
    int b   = tile_id >> 6;               // 64 row-tiles per batch
    int ty0 = (tile_id & 63) * TH;

    int tid = threadIdx.x;                // 0..255
    int xg  = tid * 2;                    // my column pair

    // ---- flow loads (f32x2) + gather state (16 px/thread) ----
    const float* flow_y = flows + (size_t)b * 2 * HW + ty0 * W + xg;
    const float* flow_x = flow_y + HW;

    float dxv[TH][2], dyv[TH][2];
    int   li[TH][2];
    unsigned okm = 0;
#pragma unroll
    for (int k = 0; k < TH; ++k) {
        f32x2 fy2 = *reinterpret_cast<const f32x2*>(flow_y + k * W);
        f32x2 fx2 = *reinterpret_cast<const f32x2*>(flow_x + k * W);
#pragma unroll
        for (int j = 0; j < 2; ++j) {
            float fy = fy2[j];
            float fx = fx2[j];
            float sx = fminf(fmaxf((float)(xg + j) + fx, 0.0f), (float)(W - 1));
            float sy = fminf(fmaxf((float)(ty0 + k) + fy, 0.0f), (float)(H - 1));
            int x0 = min((int)sx, W - 2); // sx >= 0 so (int) == floor
            int y0 = min((int)sy, H - 2);
            dxv[k][j] = sx - (float)x0;
            dyv[k][j] = sy - (float)y0;
            int ly0 = y0 - (ty0 - HALO);
            bool ok = (ly0 >= 0) & (ly0 <= LROWS - 2);
            okm |= (unsigned)ok << (k * 2 + j);
            li[k][j] = ok ? (ly0 * LWP + x0)   // LDS offset
                          : (y0 * W + x0);     // global fallback offset
        }
    }
    bool fast = __all(okm == 0xFFFFu);

    // staging addresses: 256 thr x 16B = 4KB = 2 rows per instr, 8 instrs/ch
    int srow[LROWS / 2];
    int scol = (tid & 127) * 4;
#pragma unroll
    for (int it = 0; it < LROWS / 2; ++it) {
        int r = it * 2 + (tid >> 7);
        srow[it] = min(max(ty0 - HALO + r, 0), H - 1);
    }

    for (int c = 0; c < C; ++c) {
        const float* gimg = images + ((size_t)b * C + c) * HW;
        __syncthreads();                  // previous channel's reads done
#pragma unroll
        for (int it = 0; it < LROWS / 2; ++it) {
            int r = it * 2 + (tid >> 7);
            __builtin_amdgcn_global_load_lds(
                (const __attribute__((address_space(1))) void*)(gimg + srow[it] * W + scol),
                (__attribute__((address_space(3))) void*)(&tile[r * LWP + scol]),
                16, 0, 0);
        }
        __syncthreads();                  // drains vmcnt -> tile ready

        float* outc = out + ((size_t)b * C + c) * HW + ty0 * W + xg;
        if (fast) {
#pragma unroll
            for (int k = 0; k < TH; ++k) {
                f32x2 r2;
#pragma unroll
                for (int j = 0; j < 2; ++j) {
                    float dx = dxv[k][j], dy = dyv[k][j];
                    float wa = (1.0f - dx) * (1.0f - dy);
                    float wb = (1.0f - dx) * dy;
                    float wc = dx * (1.0f - dy);
                    float wd = dx * dy;
                    int t = li[k][j];
                    float Ia = tile[t];        float Ic = tile[t + 1];
                    float Ib = tile[t + LWP];  float Id = tile[t + LWP + 1];
                    r2[j] = wa * Ia + wb * Ib + wc * Ic + wd * Id;
                }
                __builtin_nontemporal_store(r2,
                    reinterpret_cast<f32x2*>(outc + k * W));
            }
        } else {                           // rare: |dy| > ~4 near strip edge
#pragma unroll
            for (int k = 0; k < TH; ++k) {
                f32x2 r2;
#pragma unroll
                for (int j = 0; j < 2; ++j) {
                    float dx = dxv[k][j], dy = dyv[k][j];
                    float wa = (1.0f - dx) * (1.0f - dy);
                    float wb = (1.0f - dx) * dy;
                    float wc = dx * (1.0f - dy);
                    float wd = dx * dy;
                    float Ia, Ib, Ic, Id;
                    if ((okm >> (k * 2 + j)) & 1) {
                        int t = li[k][j];
                        Ia = tile[t];        Ic = tile[t + 1];
                        Ib = tile[t + LWP];  Id = tile[t + LWP + 1];
                    } else {
                        int g = li[k][j];
                        Ia = gimg[g];        Ic = gimg[g + 1];
                        Ib = gimg[g + W];    Id = gimg[g + W + 1];
                    }
                    r2[j] = wa * Ia + wb * Ib + wc * Ic + wd * Id;
                }
                __builtin_nontemporal_store(r2,
                    reinterpret_cast<f32x2*>(outc + k * W));
            }
        }
    }
}

extern "C" void kernel_launch(void* const* d_in, const int* in_sizes, int n_in,
                              void* d_out, int out_size, void* d_ws, size_t ws_size,
                              hipStream_t stream) {
    const float* images = (const float*)d_in[0];
    const float* flows  = (const float*)d_in[1];
    float* out = (float*)d_out;

    dim3 block(256);
    dim3 grid(TILES);                     // 2048 blocks
    hipLaunchKernelGGL(warp_bilinear_rows, grid, block, 0, stream,
                       images, flows, out);
}